// Round 7
// baseline (700.980 us; speedup 1.0000x reference)
//
#include <hip/hip_runtime.h>
#include <hip/hip_bf16.h>
#include <math.h>

// Round 7: single fused MFMA kernel (round 6 + Hb swizzle bijectivity fix).
//  Hb row stride is 320 B (not a multiple of 128), so its XOR swizzle must be
//  (row&3)<<4 (64-B span; 320 = 5*64), NOT (row&7)<<4 -- the round-6 bug.
// B=131072, E=64, H=4, D=16, S=5. Out: (B,160) fp32.

#define NROWS 131072

typedef __attribute__((ext_vector_type(8))) short short8;
typedef __attribute__((ext_vector_type(4))) float f32x4;

__device__ __forceinline__ short f2bs(float f) {
  __hip_bfloat16 h = __float2bfloat16(f);
  return *reinterpret_cast<short*>(&h);
}
__device__ __forceinline__ float bs2f(short s) {
  union { unsigned u; float f; } c;
  c.u = ((unsigned)(unsigned short)s) << 16;
  return c.f;
}

#define MFMA __builtin_amdgcn_mfma_f32_16x16x32_bf16

// ---------------- pack 1: W1,W2 -> bf16 fragment-ordered (proven) ----------------
__global__ void pack_weights(const float* __restrict__ W1, const float* __restrict__ W2,
                             short* __restrict__ ws) {
  int idx = blockIdx.x * blockDim.x + threadIdx.x;
  if (idx < 81920) {
    int i = idx & 7, lane = (idx >> 3) & 63;
    int t = idx >> 9;                 // ntg*10 + kk
    int kk = t % 10, ntg = t / 10;
    int n = ntg * 16 + (lane & 15);
    int k = kk * 32 + (lane >> 4) * 8 + i;
    ws[idx] = f2bs(W1[k * 256 + n]);
  } else if (idx < 81920 + 40960) {
    int j = idx - 81920;
    int i = j & 7, lane = (j >> 3) & 63;
    int t = j >> 9;                   // ntg*8 + kk
    int kk = t & 7, ntg = t >> 3;
    int n = ntg * 16 + (lane & 15);
    int k = kk * 32 + (lane >> 4) * 8 + i;
    ws[81920 + j] = f2bs(W2[k * 160 + n]);
  }
}

// ---------------- pack 2: front weight tables (unchanged from round 6) ----------------
__global__ void pack2(
    const float* __restrict__ Wv_p, const float* __restrict__ Wa_p,
    const float* __restrict__ Wp_p, const float* __restrict__ Ws_p,
    const float* __restrict__ Wt_p,
    const float* __restrict__ bv_p, const float* __restrict__ ba_p,
    const float* __restrict__ bp_p, const float* __restrict__ bs_p,
    const float* __restrict__ bt_p,
    const float* __restrict__ Wv_u, const float* __restrict__ Wa_u,
    const float* __restrict__ Wp_u, const float* __restrict__ Ws_u,
    const float* __restrict__ Wt_u,
    const float* __restrict__ bv_u, const float* __restrict__ ba_u,
    const float* __restrict__ bp_u, const float* __restrict__ bs_u,
    const float* __restrict__ bt_u,
    const float* __restrict__ Wq, const float* __restrict__ Wk,
    const float* __restrict__ Wvv,
    const float* __restrict__ bq, const float* __restrict__ bk,
    const float* __restrict__ bvv,
    const float* __restrict__ Wo, const float* __restrict__ bo,
    short* __restrict__ wsb, float* __restrict__ fb)
{
  int idx = blockIdx.x * blockDim.x + threadIdx.x;
  const float* WP[5] = {Wv_p, Wa_p, Wp_p, Ws_p, Wt_p};
  const float* BP[5] = {bv_p, ba_p, bp_p, bs_p, bt_p};
  const float* WU[5] = {Wv_u, Wa_u, Wp_u, Ws_u, Wt_u};
  const float* BU[5] = {bv_u, ba_u, bp_u, bs_u, bt_u};
  const int INs[5]  = {14, 17, 51, 7, 10};
  const int HIDs[5] = {32, 64, 32, 16, 16};
  const int KOFF[5] = {0, 16, 36, 92, 100};
  const int HOFF[5] = {0, 32, 96, 128, 144};

  if (idx < 20480) {                                   // WPbf
    int i = idx & 7, lane = (idx >> 3) & 63, rest = idx >> 9;   // rest<40
    int kt = rest / 10, ct = rest % 10;
    int k = kt * 32 + (lane >> 4) * 8 + i;
    int n = ct * 16 + (lane & 15);
    int s = (n < 32) ? 0 : (n < 96) ? 1 : (n < 128) ? 2 : (n < 144) ? 3 : 4;
    int kr = k - KOFF[s], nr = n - HOFF[s];
    float v = (kr >= 0 && kr < INs[s]) ? WP[s][kr * HIDs[s] + nr] : 0.f;
    wsb[122880 + idx] = f2bs(v);
  } else if (idx < 71680) {                            // WUbf
    int j2 = idx - 20480;
    int i = j2 & 7, lane = (j2 >> 3) & 63, rest = j2 >> 9;      // rest<100
    int kt = rest / 20, ct = rest % 20;
    int j = kt * 32 + (lane >> 4) * 8 + i;
    int c = ct * 16 + (lane & 15);
    int s = c >> 6, e = c & 63;
    int jr = j - HOFF[s];
    float v = (jr >= 0 && jr < HIDs[s]) ? WU[s][jr * 64 + e] : 0.f;
    wsb[143360 + j2] = f2bs(v);
  } else if (idx < 225280) {                           // WFbf
    int j2 = idx - 71680;
    int i = j2 & 7, lane = (j2 >> 3) & 63, rest = j2 >> 9;      // rest<300
    int kt = rest / 60, ct = rest % 60;
    int j = kt * 32 + (lane >> 4) * 8 + i;
    int c = ct * 16 + (lane & 15);
    int s = c / 192; int rem = c - s * 192; int t = rem >> 6, hd = rem & 63;
    int jr = j - HOFF[s];
    float v = 0.f;
    if (jr >= 0 && jr < HIDs[s]) {
      const float* wt = (t == 0) ? Wq : (t == 1) ? Wk : Wvv;
      float acc = 0.f;
      for (int e = 0; e < 64; ++e) acc += WU[s][jr * 64 + e] * wt[e * 64 + hd];
      v = acc;
    }
    wsb[194560 + j2] = f2bs(v);
  } else if (idx < 229376) {                           // WObf
    int j2 = idx - 225280;
    int i = j2 & 7, lane = (j2 >> 3) & 63, rest = j2 >> 9;      // rest<8
    int kt = rest >> 2, ct = rest & 3;
    int hd = kt * 32 + (lane >> 4) * 8 + i;
    int e = ct * 16 + (lane & 15);
    wsb[348160 + j2] = f2bs(Wo[hd * 64 + e]);
  } else if (idx < 229536) {                           // bpbig
    int n = idx - 229376;
    int s = (n < 32) ? 0 : (n < 96) ? 1 : (n < 128) ? 2 : (n < 144) ? 3 : 4;
    fb[n] = BP[s][n - HOFF[s]];
  } else if (idx < 230496) {                           // bqkvb
    int c = idx - 229536;
    int s = c / 192, rem = c % 192, t = rem >> 6, hd = rem & 63;
    const float* wt = (t == 0) ? Wq : (t == 1) ? Wk : Wvv;
    const float* bt = (t == 0) ? bq : (t == 1) ? bk : bvv;
    float acc = bt[hd];
    for (int e = 0; e < 64; ++e) acc += BU[s][e] * wt[e * 64 + hd];
    fb[160 + c] = acc;
  } else if (idx < 230816) {                           // bres
    int c = idx - 230496;
    int s = c >> 6, e = c & 63;
    fb[1120 + c] = BU[s][e] + bo[e];
  }
}

// ================= fused kernel =================
__global__ __launch_bounds__(320, 2) void ace_all(
    const float* __restrict__ visual, const float* __restrict__ audio,
    const float* __restrict__ pose,   const float* __restrict__ spatial,
    const float* __restrict__ timex,
    const float* __restrict__ gamma, const float* __restrict__ beta,
    const float* __restrict__ b1, const float* __restrict__ b2,
    const short* __restrict__ WS, const float* __restrict__ FB,
    float* __restrict__ out)
{
  __shared__ char smem[81920];
  char* INb  = smem;            // [64][256B] bf16 (swz row&7)
  char* QKV8 = smem;            // [8][1920B] bf16 (swz row&7), overlays INb
  char* O8   = smem + 15360;    // [40][128B] bf16 (swz row&7)
  char* Hb   = smem + 20480;    // [64][320B] bf16 (swz row&3 -- 320 = 5*64, NOT *128)
  char* FLAT = smem + 40960;    // [64][640B] bf16 (swz row&7)
  char* FUS  = smem;            // [64][512B] bf16 (swz row&7), MLP1 -> MLP2
  char* COUT = smem + 40960;    // [64][640B] f32  (swz row&7), MLP2 -> epilogue

  const short* W1F  = WS;
  const short* W2F  = WS + 81920;
  const short* WPbf = WS + 122880;
  const short* WUbf = WS + 143360;
  const short* WFbf = WS + 194560;
  const short* WObf = WS + 348160;
  const float* bpbig = FB;
  const float* bqkvb = FB + 160;
  const float* bres  = FB + 1120;

  const int tid  = threadIdx.x;
  const int wv   = tid >> 6;          // 0..4 == token s
  const int lane = tid & 63;
  const int r15  = lane & 15, g4 = lane >> 4;
  const int rowBase = blockIdx.x * 64;

  // ---------- zero IN ----------
  for (int i = tid; i < 4096; i += 320) ((float*)INb)[i] = 0.f;
  __syncthreads();
  // ---------- stage inputs (f32 global -> bf16 LDS, swizzled) ----------
  {
    const float* SRC[5] = {visual, audio, pose, spatial, timex};
    const int C[5] = {14, 17, 51, 7, 10};
    const int KO[5] = {0, 16, 36, 92, 100};
    #pragma unroll
    for (int md = 0; md < 5; ++md) {
      const float* src = SRC[md];
      const int c = C[md], ko = KO[md];
      for (int i = tid; i < 64 * c; i += 320) {
        int row = i / c, col = i - row * c;
        *(short*)(INb + row * 256 + (((ko + col) * 2) ^ ((row & 7) << 4))) =
            f2bs(src[(size_t)(rowBase + row) * c + col]);
      }
    }
  }
  __syncthreads();

  // ---------- proj: H[64][160] = relu(IN @ WPbig + bp) ----------
  {
    #pragma unroll
    for (int cc = 0; cc < 2; ++cc) {
      const int ct = wv * 2 + cc;
      const int pk0 = (ct < 6) ? 0 : (ct < 8) ? 1 : (ct == 8) ? 2 : 3;
      const int pk1 = (ct < 2) ? 1 : (ct < 6) ? 2 : (ct < 8) ? 3 : 4;
      f32x4 acc[4] = {};
      for (int kk = pk0; kk < pk1; ++kk) {
        short8 b = *(const short8*)(WPbf + ((kk * 10 + ct) * 64 + lane) * 8);
        #pragma unroll
        for (int mt = 0; mt < 4; ++mt) {
          int row = mt * 16 + r15;
          short8 a = *(const short8*)(INb + row * 256 + ((kk * 64 + g4 * 16) ^ ((row & 7) << 4)));
          acc[mt] = MFMA(a, b, acc[mt], 0, 0, 0);
        }
      }
      const int n = ct * 16 + r15;
      const float bias = bpbig[n];
      #pragma unroll
      for (int mt = 0; mt < 4; ++mt)
        #pragma unroll
        for (int j = 0; j < 4; ++j) {
          int row = mt * 16 + 4 * g4 + j;
          *(short*)(Hb + row * 320 + ((n * 2) ^ ((row & 3) << 4))) =   // swz &3
              f2bs(fmaxf(acc[mt][j] + bias, 0.f));
        }
    }
  }
  __syncthreads();

  // ---------- per-wave preloads ----------
  const int kt0 = (wv == 0) ? 0 : (wv == 1) ? 1 : (wv == 2) ? 3 : 4;
  const int kt1 = (wv == 0) ? 1 : (wv == 1) ? 3 : (wv == 2) ? 4 : 5;
  const int rs8 = (wv == 4) ? 7 : 2 * wv;
  const int re8 = rs8 + ((wv < 3) ? 2 : 1);
  float qb[12], bres_r[4], gam[4], bet[4];
  #pragma unroll
  for (int tt = 0; tt < 12; ++tt) qb[tt] = bqkvb[wv * 192 + tt * 16 + r15];
  #pragma unroll
  for (int et = 0; et < 4; ++et) {
    bres_r[et] = bres[wv * 64 + et * 16 + r15];
    gam[et] = gamma[et * 16 + r15];
    bet[et] = beta[et * 16 + r15];
  }

  // ---------- eighth loop: 8 rows each {ups+QKV | attn | Wo+LN} ----------
  for (int e8 = 0; e8 < 8; ++e8) {
    f32x4 xa[4] = {};       // x fragments (rows e8*8+4g4+j valid for g4<2)
    {
      f32x4 qa[12] = {};
      for (int kk = kt0; kk < kt1; ++kk) {
        int arow = e8 * 8 + r15;    // A rows 8..15 garbage -> C rows 8..15 discarded
        short8 a = *(const short8*)(Hb + arow * 320 + ((kk * 64 + g4 * 16) ^ ((arow & 3) << 4)));  // swz &3
        #pragma unroll
        for (int et = 0; et < 4; ++et) {
          short8 b = *(const short8*)(WUbf + ((kk * 20 + wv * 4 + et) * 64 + lane) * 8);
          xa[et] = MFMA(a, b, xa[et], 0, 0, 0);
        }
        #pragma unroll
        for (int tt = 0; tt < 12; ++tt) {
          short8 b = *(const short8*)(WFbf + ((kk * 60 + wv * 12 + tt) * 64 + lane) * 8);
          qa[tt] = MFMA(a, b, qa[tt], 0, 0, 0);
        }
      }
      if (g4 < 2) {
        #pragma unroll
        for (int tt = 0; tt < 12; ++tt) {
          int col2 = (wv * 192 + tt * 16 + r15) * 2;
          #pragma unroll
          for (int j = 0; j < 4; ++j) {
            int r = 4 * g4 + j;
            *(short*)(QKV8 + r * 1920 + (col2 ^ ((r & 7) << 4))) = f2bs(qa[tt][j] + qb[tt]);
          }
        }
      }
    }
    __syncthreads();

    // attention (lane = h*16+d), rows split {2,2,2,1,1}
    for (int r = rs8; r < re8; ++r) {
      const char* rp = QKV8 + r * 1920;
      const int sw = (r & 7) << 4;
      float q[5], k[5], v[5];
      #pragma unroll
      for (int s2 = 0; s2 < 5; ++s2) {
        q[s2] = bs2f(*(const short*)(rp + (((s2 * 192 + lane) * 2) ^ sw)));
        k[s2] = bs2f(*(const short*)(rp + (((s2 * 192 + 64 + lane) * 2) ^ sw)));
        v[s2] = bs2f(*(const short*)(rp + (((s2 * 192 + 128 + lane) * 2) ^ sw)));
      }
      #pragma unroll
      for (int qi = 0; qi < 5; ++qi) {
        float sc[5];
        #pragma unroll
        for (int ki = 0; ki < 5; ++ki) {
          float p = q[qi] * k[ki];
          p += __shfl_xor(p, 1); p += __shfl_xor(p, 2);
          p += __shfl_xor(p, 4); p += __shfl_xor(p, 8);
          sc[ki] = p * 0.25f;
        }
        float mx = fmaxf(fmaxf(fmaxf(sc[0], sc[1]), fmaxf(sc[2], sc[3])), sc[4]);
        float ss = 0.f;
        #pragma unroll
        for (int ki = 0; ki < 5; ++ki) { sc[ki] = __expf(sc[ki] - mx); ss += sc[ki]; }
        float o = 0.f;
        #pragma unroll
        for (int ki = 0; ki < 5; ++ki) o += sc[ki] * v[ki];
        o /= ss;
        int orow = r * 5 + qi;
        *(short*)(O8 + orow * 128 + ((lane * 2) ^ ((orow & 7) << 4))) = f2bs(o);
      }
    }
    __syncthreads();

    // Wo: attended frags for token wv (C rows 8..15 discarded)
    f32x4 af[4] = {};
    #pragma unroll
    for (int kk = 0; kk < 2; ++kk) {
      int orow = r15 * 5 + wv;
      short8 a = *(const short8*)(O8 + orow * 128 + ((kk * 64 + g4 * 16) ^ ((orow & 7) << 4)));
      #pragma unroll
      for (int et = 0; et < 4; ++et) {
        short8 b = *(const short8*)(WObf + ((kk * 4 + et) * 64 + lane) * 8);
        af[et] = MFMA(a, b, af[et], 0, 0, 0);
      }
    }
    // residual + LayerNorm -> FLAT (rows e8*8 + 4g4+j, g4<2)
    if (g4 < 2) {
      #pragma unroll
      for (int j = 0; j < 4; ++j) {
        float h[4], s1 = 0.f, s2 = 0.f;
        #pragma unroll
        for (int et = 0; et < 4; ++et) {
          h[et] = xa[et][j] + af[et][j] + bres_r[et];
          s1 += h[et]; s2 += h[et] * h[et];
        }
        s1 += __shfl_xor(s1, 1); s2 += __shfl_xor(s2, 1);
        s1 += __shfl_xor(s1, 2); s2 += __shfl_xor(s2, 2);
        s1 += __shfl_xor(s1, 4); s2 += __shfl_xor(s2, 4);
        s1 += __shfl_xor(s1, 8); s2 += __shfl_xor(s2, 8);
        float mean = s1 * 0.015625f;
        float var  = s2 * 0.015625f - mean * mean;
        float rs = rsqrtf(var + 1e-3f);
        int row = e8 * 8 + 4 * g4 + j;
        #pragma unroll
        for (int et = 0; et < 4; ++et) {
          float hn = (h[et] - mean) * rs * gam[et] + bet[et];
          *(short*)(FLAT + row * 640 + (((wv * 64 + et * 16 + r15) * 2) ^ ((row & 7) << 4))) =
              f2bs(hn);
        }
      }
    }
  }
  __syncthreads();

  // ---------- MLP1: FUS[64][256] = relu(FLAT @ W1 + b1) ----------
  {
    const int n0 = wv * 3;
    const int nn = (wv == 4) ? 4 : 3;
    f32x4 acc[4][4] = {};
    for (int kk = 0; kk < 10; ++kk) {
      short8 b[4];
      #pragma unroll
      for (int t = 0; t < 4; ++t)
        if (t < nn) b[t] = *(const short8*)(W1F + (((n0 + t) * 10 + kk) * 64 + lane) * 8);
      #pragma unroll
      for (int mt = 0; mt < 4; ++mt) {
        int row = mt * 16 + r15;
        short8 a = *(const short8*)(FLAT + row * 640 + ((kk * 64 + g4 * 16) ^ ((row & 7) << 4)));
        #pragma unroll
        for (int t = 0; t < 4; ++t)
          if (t < nn) acc[mt][t] = MFMA(a, b[t], acc[mt][t], 0, 0, 0);
      }
    }
    __syncthreads();   // FLAT reads done before FUS (disjoint) -- kept for phase clarity
    #pragma unroll
    for (int t = 0; t < 4; ++t) {
      if (t < nn) {
        int c = (n0 + t) * 16 + r15;
        float bias = b1[c];
        #pragma unroll
        for (int mt = 0; mt < 4; ++mt)
          #pragma unroll
          for (int j = 0; j < 4; ++j) {
            int row = mt * 16 + 4 * g4 + j;
            *(short*)(FUS + row * 512 + ((c * 2) ^ ((row & 7) << 4))) =
                f2bs(fmaxf(acc[mt][t][j] + bias, 0.f));
          }
      }
    }
  }
  __syncthreads();

  // ---------- MLP2: COUT[64][160] = relu(FUS @ W2 + b2) ----------
  {
    f32x4 acc[4][2] = {};
    for (int kk = 0; kk < 8; ++kk) {
      short8 b0 = *(const short8*)(W2F + (((wv * 2) * 8 + kk) * 64 + lane) * 8);
      short8 b1f = *(const short8*)(W2F + (((wv * 2 + 1) * 8 + kk) * 64 + lane) * 8);
      #pragma unroll
      for (int mt = 0; mt < 4; ++mt) {
        int row = mt * 16 + r15;
        short8 a = *(const short8*)(FUS + row * 512 + ((kk * 64 + g4 * 16) ^ ((row & 7) << 4)));
        acc[mt][0] = MFMA(a, b0, acc[mt][0], 0, 0, 0);
        acc[mt][1] = MFMA(a, b1f, acc[mt][1], 0, 0, 0);
      }
    }
    __syncthreads();   // all FUS reads done; COUT overlays FLAT (already dead)
    #pragma unroll
    for (int t = 0; t < 2; ++t) {
      int c = (wv * 2 + t) * 16 + r15;
      float bias = b2[c];
      #pragma unroll
      for (int mt = 0; mt < 4; ++mt)
        #pragma unroll
        for (int j = 0; j < 4; ++j) {
          int row = mt * 16 + 4 * g4 + j;
          *(float*)(COUT + row * 640 + ((c * 4) ^ ((row & 7) << 4))) =
              fmaxf(acc[mt][t][j] + bias, 0.f);
        }
    }
  }
  __syncthreads();

  // ---------- coalesced epilogue ----------
  #pragma unroll
  for (int u = 0; u < 8; ++u) {
    int g = u * 320 + tid;            // 0..2559 f32x4 slots
    int row = g / 40, c4 = g - row * 40;
    f32x4 val = *(const f32x4*)(COUT + row * 640 + ((c4 * 16) ^ ((row & 7) << 4)));
    *(f32x4*)(out + (size_t)(rowBase + row) * 160 + c4 * 4) = val;
  }
}

extern "C" void kernel_launch(void* const* d_in, const int* in_sizes, int n_in,
                              void* d_out, int out_size, void* d_ws, size_t ws_size,
                              hipStream_t stream) {
  const float* visual  = (const float*)d_in[0];
  const float* audio   = (const float*)d_in[1];
  const float* pose    = (const float*)d_in[2];
  const float* spatial = (const float*)d_in[3];
  const float* timex   = (const float*)d_in[4];
  const float* Wv_p = (const float*)d_in[5];  const float* bv_p = (const float*)d_in[6];
  const float* Wa_p = (const float*)d_in[7];  const float* ba_p = (const float*)d_in[8];
  const float* Wp_p = (const float*)d_in[9];  const float* bp_p = (const float*)d_in[10];
  const float* Ws_p = (const float*)d_in[11]; const float* bs_p = (const float*)d_in[12];
  const float* Wt_p = (const float*)d_in[13]; const float* bt_p = (const float*)d_in[14];
  const float* Wv_u = (const float*)d_in[15]; const float* bv_u = (const float*)d_in[16];
  const float* Wa_u = (const float*)d_in[17]; const float* ba_u = (const float*)d_in[18];
  const float* Wp_u = (const float*)d_in[19]; const float* bp_u = (const float*)d_in[20];
  const float* Ws_u = (const float*)d_in[21]; const float* bs_u = (const float*)d_in[22];
  const float* Wt_u = (const float*)d_in[23]; const float* bt_u = (const float*)d_in[24];
  const float* Wq  = (const float*)d_in[25];  const float* bq  = (const float*)d_in[26];
  const float* Wk  = (const float*)d_in[27];  const float* bk  = (const float*)d_in[28];
  const float* Wvv = (const float*)d_in[29];  const float* bvv = (const float*)d_in[30];
  const float* Wo  = (const float*)d_in[31];  const float* bo  = (const float*)d_in[32];
  const float* gamma = (const float*)d_in[33]; const float* beta = (const float*)d_in[34];
  const float* W1 = (const float*)d_in[35];   const float* b1 = (const float*)d_in[36];
  const float* W2 = (const float*)d_in[37];   const float* b2 = (const float*)d_in[38];
  float* out = (float*)d_out;

  short* WS = (short*)d_ws;                        // bf16 tables, bytes [0, 704512)
  float* FB = (float*)((char*)d_ws + 704512);      // f32 tables, 1440 floats

  hipLaunchKernelGGL(pack_weights, dim3(480), dim3(256), 0, stream, W1, W2, WS);
  hipLaunchKernelGGL(pack2, dim3(902), dim3(256), 0, stream,
                     Wv_p, Wa_p, Wp_p, Ws_p, Wt_p,
                     bv_p, ba_p, bp_p, bs_p, bt_p,
                     Wv_u, Wa_u, Wp_u, Ws_u, Wt_u,
                     bv_u, ba_u, bp_u, bs_u, bt_u,
                     Wq, Wk, Wvv, bq, bk, bvv, Wo, bo, WS, FB);

  hipLaunchKernelGGL(ace_all, dim3(NROWS / 64), dim3(320), 0, stream,
                     visual, audio, pose, spatial, timex,
                     gamma, beta, b1, b2, WS, FB, out);
}